// Round 12
// baseline (380.756 us; speedup 1.0000x reference)
//
#include <hip/hip_runtime.h>

#define NN 100000      // nodes
#define NE 400000      // edges per direction
#define NE2 800000
#define C 200          // channels
#define NREL 475       // 2*237 + loop
#define NB 50          // basis
#define KP 224         // K padded to 7*32
#define NTP 256        // N rows per mat in wt, padded (208 used, rest zero)
#define NSCAN_BLKS ((2 * NN + 255) / 256)   // 782

typedef __attribute__((ext_vector_type(8))) short short8;
typedef __attribute__((ext_vector_type(4))) float f32x4;
typedef __attribute__((ext_vector_type(2))) float f32x2;
typedef __attribute__((ext_vector_type(2))) unsigned u32x2;

// workspace layout (u32 word offsets), total ~130 MB
#define W_RE     0L          // 95,000 f32  rel_emb
#define W_DINV   95104L      // 200,000 f32 [dir*NN+node]
#define W_DEG    295104L     // 200,000 int (deg, reused as scatter cursor)
#define W_OFFS   495104L     // 200,001 int CSR offsets
#define W_PSUM   695200L     // 1,024 int
#define W_BUCKET 696320L     // 800,000 u32 packed (tail<<9 | type)
#define W_BNORM  1496320L    // 800,000 f32 per-edge norm (parallel to bucket)
#define W_AGG    2296320L    // (3*NN+128)*100 u32 bf16-pairs: [agg_in | agg_out | x-loop], padded
#define W_WT     32309120L   // 86,016 u32 = 3*256*224 bf16 (N-padded weights^T)
#define W_REB    32395264L   // 47,500 u32 bf16 (re - loop_rel) [475][100]

__device__ __forceinline__ unsigned short f2bf(float f) {
  unsigned u = __builtin_bit_cast(unsigned, f);
  return (unsigned short)((u + 0x7FFFu + ((u >> 16) & 1u)) >> 16);  // RNE
}
__device__ __forceinline__ unsigned pack2(float a, float b) {
  return (unsigned)f2bf(a) | ((unsigned)f2bf(b) << 16);
}
__device__ __forceinline__ float bf_lo(unsigned w) { return __builtin_bit_cast(float, w << 16); }
__device__ __forceinline__ float bf_hi(unsigned w) { return __builtin_bit_cast(float, w & 0xFFFF0000u); }

// ---- precompute (VERBATIM from R11) -----------------------------------------

__global__ void k_relemb(const float* rw, const float* basis, const float* loop_rel, float* re) {
  __shared__ float row[NB];
  int r = blockIdx.x, j = threadIdx.x;
  if (r == NREL - 1) {
    if (j < C) re[(size_t)r * C + j] = loop_rel[j];
    return;
  }
  if (j < NB) row[j] = rw[r * NB + j];
  __syncthreads();
  if (j < C) {
    float a = 0.f;
    #pragma unroll 5
    for (int b = 0; b < NB; b++) a += row[b] * basis[b * C + j];
    re[(size_t)r * C + j] = a;
  }
}

__global__ void k_out2(const float* re, const float* wrel, float* out2) {
  __shared__ float row[C];
  int b = blockIdx.x, j = threadIdx.x;
  if (j < C) row[j] = re[(size_t)b * C + j];
  __syncthreads();
  if (j < C) {
    float a = 0.f;
    #pragma unroll 4
    for (int k = 0; k < C; k++) a += row[k] * wrel[k * C + j];
    out2[(size_t)b * C + j] = a;
  }
}

__global__ void k_wt(const float* w_in, const float* w_out, const float* w_loop, short* wt) {
  int i = blockIdx.x * blockDim.x + threadIdx.x;
  if (i >= 3 * NTP * KP) return;
  int m = i / (NTP * KP);
  int r = i % (NTP * KP);
  int n = r / KP, k = r % KP;
  const float* W = (m == 0) ? w_in : (m == 1) ? w_out : w_loop;
  float v = (n < C && k < C) ? W[k * C + n] : 0.f;
  wt[i] = (short)f2bf(v);
}

// agg section 2 = bf16(x - loop_rel)
__global__ void k_xloop(const float* x, const float* loop_rel, unsigned* agg2) {
  int i = blockIdx.x * blockDim.x + threadIdx.x;
  if (i >= NN * 100) return;
  int n = i / 100, w = i - n * 100;
  int ch = 2 * w;
  f32x2 v = *(const f32x2*)(x + (size_t)n * C + ch);
  f32x2 l = *(const f32x2*)(loop_rel + ch);
  agg2[i] = pack2(v[0] - l[0], v[1] - l[1]);
}

// reb = bf16(re - loop_rel), [475][100] words
__global__ void k_reb(const float* re, const float* loop_rel, unsigned* reb) {
  int i = blockIdx.x * blockDim.x + threadIdx.x;
  if (i >= NREL * 100) return;
  int r = i / 100, w = i - r * 100;
  int ch = 2 * w;
  f32x2 v = *(const f32x2*)(re + (size_t)r * C + ch);
  f32x2 l = *(const f32x2*)(loop_rel + ch);
  reb[i] = pack2(v[0] - l[0], v[1] - l[1]);
}

// ---- CSR construction (VERBATIM from R11) -----------------------------------

__global__ void k_deg(const int* ei, int* deg) {
  int c = blockIdx.x * blockDim.x + threadIdx.x;
  if (c >= NE2) return;
  atomicAdd(deg + (c < NE ? 0 : NN) + ei[c], 1);
}

__global__ void k_dinv(const int* deg, float* dinv) {
  int i = blockIdx.x * blockDim.x + threadIdx.x;
  if (i >= 2 * NN) return;
  int v = deg[i];
  dinv[i] = (v > 0) ? rsqrtf((float)v) : 0.f;
}

__global__ void k_scan1(const int* deg, int* psum) {
  __shared__ int s[256];
  int t = threadIdx.x, i = blockIdx.x * 256 + t;
  s[t] = (i < 2 * NN) ? deg[i] : 0;
  __syncthreads();
  for (int off = 128; off > 0; off >>= 1) {
    if (t < off) s[t] += s[t + off];
    __syncthreads();
  }
  if (t == 0) psum[blockIdx.x] = s[0];
}

__global__ void k_scan2(int* psum) {
  __shared__ int s[1024];
  int t = threadIdx.x;
  int v = (t < NSCAN_BLKS) ? psum[t] : 0;
  s[t] = v;
  __syncthreads();
  for (int off = 1; off < 1024; off <<= 1) {
    int x = (t >= off) ? s[t - off] : 0;
    __syncthreads();
    s[t] += x;
    __syncthreads();
  }
  if (t < NSCAN_BLKS) psum[t] = s[t] - v;  // exclusive
}

__global__ void k_scan3(const int* deg, const int* psum, int* offs, int* cursor) {
  __shared__ int s[256];
  int t = threadIdx.x, i = blockIdx.x * 256 + t;
  int v = (i < 2 * NN) ? deg[i] : 0;
  s[t] = v;
  __syncthreads();
  for (int off = 1; off < 256; off <<= 1) {
    int x = (t >= off) ? s[t - off] : 0;
    __syncthreads();
    s[t] += x;
    __syncthreads();
  }
  if (i < 2 * NN) {
    int o = psum[blockIdx.x] + s[t] - v;
    offs[i] = o;
    cursor[i] = o;
  }
  if (i == 0) offs[2 * NN] = NE2;
}

__global__ void k_scatter(const int* ei, const int* et, const float* dinv,
                          int* cursor, unsigned* bucket, float* bnorm) {
  int c = blockIdx.x * blockDim.x + threadIdx.x;
  if (c >= NE2) return;
  int head = ei[c];
  int tail = ei[NE2 + c];
  int ty = et[c];
  int base = (c < NE) ? 0 : NN;
  float nm = dinv[base + head] * dinv[base + tail];
  int pos = atomicAdd(cursor + base + head, 1);
  bucket[pos] = ((unsigned)tail << 9) | (unsigned)ty;
  bnorm[pos] = nm;
}

// ---- gather -- DELTA: lane<50 x u32x2 row loads + __restrict__ --------------
// R7 loop structure (scalar bucket[p]/bnorm[p] per iteration, same edge order).
// Lane l<50 covers channels 4l..4l+3: one 8B load per row per edge.

__global__ __launch_bounds__(256) void k_gather(const unsigned* __restrict__ bucket,
                                                const int* __restrict__ offs,
                                                const float* __restrict__ bnorm,
                                                const unsigned* __restrict__ xb,
                                                const unsigned* __restrict__ reb,
                                                unsigned* __restrict__ agg) {
  int wid = (blockIdx.x * blockDim.x + threadIdx.x) >> 6;
  if (wid >= 2 * NN) return;
  int lane = threadIdx.x & 63;
  int s = offs[wid], e = offs[wid + 1];
  bool act = lane < 50;
  int wo = 2 * lane;                 // words wo, wo+1 -> channels 4l..4l+3
  float a0 = 0.f, a1 = 0.f, a2 = 0.f, a3 = 0.f;
  for (int p = s; p < e; ++p) {
    unsigned w = bucket[p];
    int tail = (int)(w >> 9);
    int ty = (int)(w & 511u);
    float nm = bnorm[p];
    if (act) {
      u32x2 xv = *(const u32x2*)(xb + (size_t)tail * 100 + wo);
      u32x2 rv = *(const u32x2*)(reb + (size_t)ty * 100 + wo);
      a0 += nm * (bf_lo(xv[0]) - bf_lo(rv[0]));
      a1 += nm * (bf_hi(xv[0]) - bf_hi(rv[0]));
      a2 += nm * (bf_lo(xv[1]) - bf_lo(rv[1]));
      a3 += nm * (bf_hi(xv[1]) - bf_hi(rv[1]));
    }
  }
  if (act) {
    u32x2 o;
    o[0] = pack2(a0, a1);
    o[1] = pack2(a2, a3);
    *(u32x2*)(agg + (size_t)wid * 100 + wo) = o;
  }
}

// ---- fused triple matmul + tanh (VERBATIM from R11-passing kernel) ----------

__global__ __launch_bounds__(256, 4) void k_mm(const unsigned* agg, const short* wt,
                                               float* out) {
  int wave = threadIdx.x >> 6;
  int lane = threadIdx.x & 63;
  int m = lane & 15, kq = lane >> 4;
  int row0 = blockIdx.x * 64;
  int n0 = wave * 64;

  f32x4 acc[4][4];
  #pragma unroll
  for (int s = 0; s < 4; s++)
    #pragma unroll
    for (int t = 0; t < 4; t++) acc[s][t] = (f32x4)(0.f);

  for (int mat = 0; mat < 3; mat++) {
    const unsigned* abase = agg + ((size_t)mat * NN + row0 + m) * 100 + kq * 4;
    const short*    wb    = wt + ((size_t)mat * NTP + n0 + m) * KP + kq * 8;
    #pragma unroll
    for (int ks = 0; ks < 7; ks++) {
      short8 A[4], B[4];
      #pragma unroll
      for (int s = 0; s < 4; s++)
        A[s] = *(const short8*)(abase + (size_t)s * 16 * 100 + ks * 16);
      #pragma unroll
      for (int t = 0; t < 4; t++)
        B[t] = *(const short8*)(wb + (size_t)t * 16 * KP + ks * 32);
      #pragma unroll
      for (int s = 0; s < 4; s++)
        #pragma unroll
        for (int t = 0; t < 4; t++)
          acc[s][t] = __builtin_amdgcn_mfma_f32_16x16x32_bf16(A[s], B[t], acc[s][t], 0, 0, 0);
    }
  }

  #pragma unroll
  for (int s = 0; s < 4; s++) {
    int r0 = row0 + s * 16 + kq * 4;   // D: col = lane&15, row = 4*kq + reg
    #pragma unroll
    for (int t = 0; t < 4; t++) {
      int n = n0 + t * 16 + m;
      if (n >= C) continue;
      #pragma unroll
      for (int j = 0; j < 4; j++) {
        int r = r0 + j;
        if (r < NN) out[(size_t)r * C + n] = tanhf(acc[s][t][j] * (1.f / 3.f));
      }
    }
  }
}

// -----------------------------------------------------------------------------

extern "C" void kernel_launch(void* const* d_in, const int* in_sizes, int n_in,
                              void* d_out, int out_size, void* d_ws, size_t ws_size,
                              hipStream_t stream) {
  const float* X        = (const float*)d_in[0];
  const int*   ei       = (const int*)d_in[1];
  const int*   et       = (const int*)d_in[2];
  const float* basis    = (const float*)d_in[3];
  const float* relw     = (const float*)d_in[4];
  const float* wrel     = (const float*)d_in[5];
  const float* loop_rel = (const float*)d_in[6];
  const float* w_in     = (const float*)d_in[7];
  const float* w_out    = (const float*)d_in[8];
  const float* w_loop   = (const float*)d_in[9];

  float* out = (float*)d_out;
  float* ws  = (float*)d_ws;

  float*    re     = ws + W_RE;
  float*    dinv   = ws + W_DINV;
  int*      deg    = (int*)(ws + W_DEG);     // reused as scatter cursor
  int*      offs   = (int*)(ws + W_OFFS);
  int*      psum   = (int*)(ws + W_PSUM);
  unsigned* bucket = (unsigned*)(ws + W_BUCKET);
  float*    bnorm  = ws + W_BNORM;
  unsigned* agg    = (unsigned*)(ws + W_AGG);
  short*    wt     = (short*)(ws + W_WT);
  unsigned* reb    = (unsigned*)(ws + W_REB);
  float*    out2   = out + (size_t)NN * C;
  unsigned* agg2   = agg + (size_t)2 * NN * 100;

  hipMemsetAsync(deg, 0, 2 * NN * sizeof(int), stream);

  k_relemb<<<NREL, 256, 0, stream>>>(relw, basis, loop_rel, re);
  k_out2<<<NREL, 256, 0, stream>>>(re, wrel, out2);
  k_reb<<<(NREL * 100 + 255) / 256, 256, 0, stream>>>(re, loop_rel, reb);
  k_wt<<<(3 * NTP * KP + 255) / 256, 256, 0, stream>>>(w_in, w_out, w_loop, wt);
  k_xloop<<<(NN * 100 + 255) / 256, 256, 0, stream>>>(X, loop_rel, agg2);

  k_deg<<<(NE2 + 255) / 256, 256, 0, stream>>>(ei, deg);
  k_dinv<<<(2 * NN + 255) / 256, 256, 0, stream>>>(deg, dinv);
  k_scan1<<<NSCAN_BLKS, 256, 0, stream>>>(deg, psum);
  k_scan2<<<1, 1024, 0, stream>>>(psum);
  k_scan3<<<NSCAN_BLKS, 256, 0, stream>>>(deg, psum, offs, deg /*cursor*/);
  k_scatter<<<(NE2 + 255) / 256, 256, 0, stream>>>(ei, et, dinv, deg /*cursor*/, bucket, bnorm);

  k_gather<<<(2 * NN) / 4, 256, 0, stream>>>(bucket, offs, bnorm, agg2, reb, agg);
  k_mm<<<(NN + 63) / 64, 256, 0, stream>>>(agg, wt, out);
}

// Round 13
// 346.886 us; speedup vs baseline: 1.0976x; 1.0976x over previous
//
#include <hip/hip_runtime.h>

#define NN 100000      // nodes
#define NE 400000      // edges per direction
#define NE2 800000
#define C 200          // channels
#define NREL 475       // 2*237 + loop
#define NB 50          // basis
#define NSCAN_BLKS ((2 * NN + 255) / 256)   // 782

typedef __attribute__((ext_vector_type(8))) short short8;
typedef __attribute__((ext_vector_type(4))) float f32x4;
typedef __attribute__((ext_vector_type(2))) float f32x2;
typedef __attribute__((ext_vector_type(2))) unsigned u32x2;
typedef __attribute__((ext_vector_type(4))) unsigned u32x4;

// workspace layout (u32 word offsets), total ~130 MB
#define W_RE     0L          // 95,000 f32  rel_emb
#define W_DINV   95104L      // 200,000 f32 [dir*NN+node]
#define W_DEG    295104L     // 200,000 int (deg, reused as scatter cursor)
#define W_OFFS   495104L     // 200,001 int CSR offsets
#define W_PSUM   695200L     // 1,024 int
#define W_BUCKET 696320L     // 800,000 u32 packed (tail<<9 | type)
#define W_BNORM  1496320L    // 800,000 f32 per-edge norm (parallel to bucket)
#define W_AGG    2296320L    // (3*NN+128)*100 u32 bf16-pairs: [agg_in | agg_out | x-loop], padded
#define W_WT     32309120L   // 86,016 u32 = 344KB fragment-major bf16 weights
#define W_REB    32395264L   // 47,500 u32 bf16 (re - loop_rel) [475][100]

__device__ __forceinline__ unsigned short f2bf(float f) {
  unsigned u = __builtin_bit_cast(unsigned, f);
  return (unsigned short)((u + 0x7FFFu + ((u >> 16) & 1u)) >> 16);  // RNE
}
__device__ __forceinline__ unsigned pack2(float a, float b) {
  return (unsigned)f2bf(a) | ((unsigned)f2bf(b) << 16);
}
__device__ __forceinline__ float bf_lo(unsigned w) { return __builtin_bit_cast(float, w << 16); }
__device__ __forceinline__ float bf_hi(unsigned w) { return __builtin_bit_cast(float, w & 0xFFFF0000u); }

// ---- precompute (k_wt REWRITTEN to fragment-major; rest VERBATIM R12) -------

__global__ void k_relemb(const float* rw, const float* basis, const float* loop_rel, float* re) {
  __shared__ float row[NB];
  int r = blockIdx.x, j = threadIdx.x;
  if (r == NREL - 1) {
    if (j < C) re[(size_t)r * C + j] = loop_rel[j];
    return;
  }
  if (j < NB) row[j] = rw[r * NB + j];
  __syncthreads();
  if (j < C) {
    float a = 0.f;
    #pragma unroll 5
    for (int b = 0; b < NB; b++) a += row[b] * basis[b * C + j];
    re[(size_t)r * C + j] = a;
  }
}

__global__ void k_out2(const float* re, const float* wrel, float* out2) {
  __shared__ float row[C];
  int b = blockIdx.x, j = threadIdx.x;
  if (j < C) row[j] = re[(size_t)b * C + j];
  __syncthreads();
  if (j < C) {
    float a = 0.f;
    #pragma unroll 4
    for (int k = 0; k < C; k++) a += row[k] * wrel[k * C + j];
    out2[(size_t)b * C + j] = a;
  }
}

// wtsw[mat][ct(16)][ks(7)][lane(64)] = 8 shorts: W[ks*32+(lane>>4)*8+j][ct*16+(lane&15)]
// (zero outside 200x200). One short8 per thread; 21,504 slots.
__global__ void k_wt(const float* w_in, const float* w_out, const float* w_loop, short* wtsw) {
  int i = blockIdx.x * blockDim.x + threadIdx.x;
  if (i >= 3 * 16 * 7 * 64) return;
  int l = i & 63;
  int rest = i >> 6;
  int ks = rest % 7;
  int rest2 = rest / 7;
  int ct = rest2 & 15;
  int mat = rest2 >> 4;
  const float* W = (mat == 0) ? w_in : (mat == 1) ? w_out : w_loop;
  int n = ct * 16 + (l & 15);
  int kb = ks * 32 + (l >> 4) * 8;
  short8 v;
  #pragma unroll
  for (int j = 0; j < 8; j++) {
    int k = kb + j;
    v[j] = (n < C && k < C) ? (short)f2bf(W[k * C + n]) : (short)0;
  }
  *(short8*)(wtsw + (size_t)i * 8) = v;
}

// agg section 2 = bf16(x - loop_rel) (VERBATIM)
__global__ void k_xloop(const float* x, const float* loop_rel, unsigned* agg2) {
  int i = blockIdx.x * blockDim.x + threadIdx.x;
  if (i >= NN * 100) return;
  int n = i / 100, w = i - n * 100;
  int ch = 2 * w;
  f32x2 v = *(const f32x2*)(x + (size_t)n * C + ch);
  f32x2 l = *(const f32x2*)(loop_rel + ch);
  agg2[i] = pack2(v[0] - l[0], v[1] - l[1]);
}

// reb = bf16(re - loop_rel), [475][100] words (VERBATIM)
__global__ void k_reb(const float* re, const float* loop_rel, unsigned* reb) {
  int i = blockIdx.x * blockDim.x + threadIdx.x;
  if (i >= NREL * 100) return;
  int r = i / 100, w = i - r * 100;
  int ch = 2 * w;
  f32x2 v = *(const f32x2*)(re + (size_t)r * C + ch);
  f32x2 l = *(const f32x2*)(loop_rel + ch);
  reb[i] = pack2(v[0] - l[0], v[1] - l[1]);
}

// ---- CSR construction (VERBATIM from R12) -----------------------------------

__global__ void k_deg(const int* ei, int* deg) {
  int c = blockIdx.x * blockDim.x + threadIdx.x;
  if (c >= NE2) return;
  atomicAdd(deg + (c < NE ? 0 : NN) + ei[c], 1);
}

__global__ void k_dinv(const int* deg, float* dinv) {
  int i = blockIdx.x * blockDim.x + threadIdx.x;
  if (i >= 2 * NN) return;
  int v = deg[i];
  dinv[i] = (v > 0) ? rsqrtf((float)v) : 0.f;
}

__global__ void k_scan1(const int* deg, int* psum) {
  __shared__ int s[256];
  int t = threadIdx.x, i = blockIdx.x * 256 + t;
  s[t] = (i < 2 * NN) ? deg[i] : 0;
  __syncthreads();
  for (int off = 128; off > 0; off >>= 1) {
    if (t < off) s[t] += s[t + off];
    __syncthreads();
  }
  if (t == 0) psum[blockIdx.x] = s[0];
}

__global__ void k_scan2(int* psum) {
  __shared__ int s[1024];
  int t = threadIdx.x;
  int v = (t < NSCAN_BLKS) ? psum[t] : 0;
  s[t] = v;
  __syncthreads();
  for (int off = 1; off < 1024; off <<= 1) {
    int x = (t >= off) ? s[t - off] : 0;
    __syncthreads();
    s[t] += x;
    __syncthreads();
  }
  if (t < NSCAN_BLKS) psum[t] = s[t] - v;  // exclusive
}

__global__ void k_scan3(const int* deg, const int* psum, int* offs, int* cursor) {
  __shared__ int s[256];
  int t = threadIdx.x, i = blockIdx.x * 256 + t;
  int v = (i < 2 * NN) ? deg[i] : 0;
  s[t] = v;
  __syncthreads();
  for (int off = 1; off < 256; off <<= 1) {
    int x = (t >= off) ? s[t - off] : 0;
    __syncthreads();
    s[t] += x;
    __syncthreads();
  }
  if (i < 2 * NN) {
    int o = psum[blockIdx.x] + s[t] - v;
    offs[i] = o;
    cursor[i] = o;
  }
  if (i == 0) offs[2 * NN] = NE2;
}

__global__ void k_scatter(const int* ei, const int* et, const float* dinv,
                          int* cursor, unsigned* bucket, float* bnorm) {
  int c = blockIdx.x * blockDim.x + threadIdx.x;
  if (c >= NE2) return;
  int head = ei[c];
  int tail = ei[NE2 + c];
  int ty = et[c];
  int base = (c < NE) ? 0 : NN;
  float nm = dinv[base + head] * dinv[base + tail];
  int pos = atomicAdd(cursor + base + head, 1);
  bucket[pos] = ((unsigned)tail << 9) | (unsigned)ty;
  bnorm[pos] = nm;
}

// ---- gather (VERBATIM from R12-passing kernel) ------------------------------

__global__ __launch_bounds__(256) void k_gather(const unsigned* __restrict__ bucket,
                                                const int* __restrict__ offs,
                                                const float* __restrict__ bnorm,
                                                const unsigned* __restrict__ xb,
                                                const unsigned* __restrict__ reb,
                                                unsigned* __restrict__ agg) {
  int wid = (blockIdx.x * blockDim.x + threadIdx.x) >> 6;
  if (wid >= 2 * NN) return;
  int lane = threadIdx.x & 63;
  int s = offs[wid], e = offs[wid + 1];
  bool act = lane < 50;
  int wo = 2 * lane;                 // words wo, wo+1 -> channels 4l..4l+3
  float a0 = 0.f, a1 = 0.f, a2 = 0.f, a3 = 0.f;
  for (int p = s; p < e; ++p) {
    unsigned w = bucket[p];
    int tail = (int)(w >> 9);
    int ty = (int)(w & 511u);
    float nm = bnorm[p];
    if (act) {
      u32x2 xv = *(const u32x2*)(xb + (size_t)tail * 100 + wo);
      u32x2 rv = *(const u32x2*)(reb + (size_t)ty * 100 + wo);
      a0 += nm * (bf_lo(xv[0]) - bf_lo(rv[0]));
      a1 += nm * (bf_hi(xv[0]) - bf_hi(rv[0]));
      a2 += nm * (bf_lo(xv[1]) - bf_lo(rv[1]));
      a3 += nm * (bf_hi(xv[1]) - bf_hi(rv[1]));
    }
  }
  if (act) {
    u32x2 o;
    o[0] = pack2(a0, a1);
    o[1] = pack2(a2, a3);
    *(u32x2*)(agg + (size_t)wid * 100 + wo) = o;
  }
}

// ---- fused triple matmul + tanh -- DELTA: LDS-staged A + fragment-major B ---
// Block = 64 rows x 4 waves (wave w owns cols [64w,64w+64)).
// Per mat: stage 64 agg rows (25.6KB) coalesced into LDS; A fragments via
// ds_read_b128 (2-way bank alias = free); B loads 1-segment coalesced 1KB.
// Operand values + accumulation order (mat,ks,s,t) identical to R12.

__global__ __launch_bounds__(256, 4) void k_mm(const unsigned* __restrict__ agg,
                                               const short* __restrict__ wt,
                                               float* __restrict__ out) {
  __shared__ __align__(16) unsigned la[6464];   // 64 rows x 100 words + pad
  int tid = threadIdx.x;
  int wave = tid >> 6;
  int lane = tid & 63;
  int m = lane & 15, kq = lane >> 4;
  int row0 = blockIdx.x * 64;

  f32x4 acc[4][4];
  #pragma unroll
  for (int s = 0; s < 4; s++)
    #pragma unroll
    for (int t = 0; t < 4; t++) acc[s][t] = (f32x4)(0.f);

  for (int mat = 0; mat < 3; mat++) {
    __syncthreads();   // previous mat's LDS reads complete
    const u32x4* src = (const u32x4*)(agg + ((size_t)mat * NN + row0) * 100);
    for (int idx = tid; idx < 1600; idx += 256)
      ((u32x4*)la)[idx] = src[idx];
    if (tid < 64) la[6400 + tid] = 0;     // pad (read by ks=6,kq>0; x0 weight)
    __syncthreads();   // staging complete

    #pragma unroll
    for (int ks = 0; ks < 7; ks++) {
      short8 A[4], B[4];
      #pragma unroll
      for (int s = 0; s < 4; s++)
        A[s] = *(const short8*)(la + (size_t)(s * 16 + m) * 100 + kq * 4 + ks * 16);
      #pragma unroll
      for (int t = 0; t < 4; t++)
        B[t] = *(const short8*)(wt + ((size_t)((mat * 16 + (wave * 4 + t)) * 7 + ks) * 64 + lane) * 8);
      #pragma unroll
      for (int s = 0; s < 4; s++)
        #pragma unroll
        for (int t = 0; t < 4; t++)
          acc[s][t] = __builtin_amdgcn_mfma_f32_16x16x32_bf16(A[s], B[t], acc[s][t], 0, 0, 0);
    }
  }

  #pragma unroll
  for (int s = 0; s < 4; s++) {
    int r0 = row0 + s * 16 + kq * 4;   // D: col = lane&15, row = 4*kq + reg
    #pragma unroll
    for (int t = 0; t < 4; t++) {
      int n = wave * 64 + t * 16 + m;
      if (n >= C) continue;
      #pragma unroll
      for (int j = 0; j < 4; j++) {
        int r = r0 + j;
        if (r < NN) out[(size_t)r * C + n] = tanhf(acc[s][t][j] * (1.f / 3.f));
      }
    }
  }
}

// -----------------------------------------------------------------------------

extern "C" void kernel_launch(void* const* d_in, const int* in_sizes, int n_in,
                              void* d_out, int out_size, void* d_ws, size_t ws_size,
                              hipStream_t stream) {
  const float* X        = (const float*)d_in[0];
  const int*   ei       = (const int*)d_in[1];
  const int*   et       = (const int*)d_in[2];
  const float* basis    = (const float*)d_in[3];
  const float* relw     = (const float*)d_in[4];
  const float* wrel     = (const float*)d_in[5];
  const float* loop_rel = (const float*)d_in[6];
  const float* w_in     = (const float*)d_in[7];
  const float* w_out    = (const float*)d_in[8];
  const float* w_loop   = (const float*)d_in[9];

  float* out = (float*)d_out;
  float* ws  = (float*)d_ws;

  float*    re     = ws + W_RE;
  float*    dinv   = ws + W_DINV;
  int*      deg    = (int*)(ws + W_DEG);     // reused as scatter cursor
  int*      offs   = (int*)(ws + W_OFFS);
  int*      psum   = (int*)(ws + W_PSUM);
  unsigned* bucket = (unsigned*)(ws + W_BUCKET);
  float*    bnorm  = ws + W_BNORM;
  unsigned* agg    = (unsigned*)(ws + W_AGG);
  short*    wt     = (short*)(ws + W_WT);
  unsigned* reb    = (unsigned*)(ws + W_REB);
  float*    out2   = out + (size_t)NN * C;
  unsigned* agg2   = agg + (size_t)2 * NN * 100;

  hipMemsetAsync(deg, 0, 2 * NN * sizeof(int), stream);

  k_relemb<<<NREL, 256, 0, stream>>>(relw, basis, loop_rel, re);
  k_out2<<<NREL, 256, 0, stream>>>(re, wrel, out2);
  k_reb<<<(NREL * 100 + 255) / 256, 256, 0, stream>>>(re, loop_rel, reb);
  k_wt<<<(3 * 16 * 7 * 64 + 255) / 256, 256, 0, stream>>>(w_in, w_out, w_loop, wt);
  k_xloop<<<(NN * 100 + 255) / 256, 256, 0, stream>>>(X, loop_rel, agg2);

  k_deg<<<(NE2 + 255) / 256, 256, 0, stream>>>(ei, deg);
  k_dinv<<<(2 * NN + 255) / 256, 256, 0, stream>>>(deg, dinv);
  k_scan1<<<NSCAN_BLKS, 256, 0, stream>>>(deg, psum);
  k_scan2<<<1, 1024, 0, stream>>>(psum);
  k_scan3<<<NSCAN_BLKS, 256, 0, stream>>>(deg, psum, offs, deg /*cursor*/);
  k_scatter<<<(NE2 + 255) / 256, 256, 0, stream>>>(ei, et, dinv, deg /*cursor*/, bucket, bnorm);

  k_gather<<<(2 * NN) / 4, 256, 0, stream>>>(bucket, offs, bnorm, agg2, reb, agg);
  k_mm<<<(NN + 63) / 64, 256, 0, stream>>>(agg, wt, out);
}